// Round 5
// baseline (949.577 us; speedup 1.0000x reference)
//
#include <hip/hip_runtime.h>

// out[i] = sum_{e: rows[e]==i} Param_W[params[e]] * x[cols[e]] + Param_b[b_params[i]]
// N = 262144, E = 16777216, NPARAMS = 1280, NB = 16.
//
// R13 post-mortem: fused slice-scan is correct & spill-free (VGPR 52, WRITE
// 33MB) but 236us ~= scan(85) + sparse-gather(~82) + streams: gather work and
// LDS atomics DON'T overlap (R10 merged showed the same sum-not-max), and
// slice-predication pays 8x gather-instruction replication. CU-side floor of
// any LDS-slice scheme ~= 180-210us kernel-sum; R9 (208) already sits there.
//
// R14: move the E adds OFF the CU - single-pass global_atomic_add (no return)
// to out[] (1MB, Infinity-Cache resident, device-scope = memory-side atomic
// units). CU side = streams (201MB ~32us) + packed x-gathers (~55us) only;
// no vals round-trip, no partials, no reduce. Unknown: memory-side f32 atomic
// throughput. >=128/cyc -> ~65us; half that -> ~130us; both beat 208.
// Predict scatter 60-140us (revert to R9 path next round if >280),
// FETCH ~200-260MB, WRITE small, total ~195-270.

#define SLICE_BITS  15
#define SLICE_SIZE  (1 << SLICE_BITS)   // 32768
#define SLICES      8
#define CHUNKS      32
#define NPARAMS_MAX 2048
#define SCAN_THREADS 1024
#define SB4         4                   // scan4 batch (R9 revert path)
#define VB          4                   // int4-groups per thread (val & scatter)

typedef float v4f __attribute__((ext_vector_type(4)));

// ---------- Kernel A: single-pass gather + global-atomic scatter ----------
__global__ __launch_bounds__(256) void scatter_atomic_kernel(
    const float* __restrict__ x, const float* __restrict__ PW, int nparams,
    const int4* __restrict__ rows4, const int4* __restrict__ cols4,
    const int4* __restrict__ params4, float* __restrict__ out)
{
    __shared__ float pw[NPARAMS_MAX];
    for (int j = threadIdx.x; j < nparams; j += 256) pw[j] = PW[j];
    __syncthreads();

    const int base = blockIdx.x * (256 * VB) + threadIdx.x;
    int4 r[VB], c[VB], p[VB];
#pragma unroll
    for (int k = 0; k < VB; ++k) {
        r[k] = rows4[base + k * 256];
        c[k] = cols4[base + k * 256];
        p[k] = params4[base + k * 256];
    }
    // packed gathers (all 64 lanes active), then fire-and-forget atomics:
    // the RMW happens at the memory-side atomic units, not the CU.
#pragma unroll
    for (int k = 0; k < VB; ++k) {
        float vx = pw[p[k].x] * x[c[k].x];
        float vy = pw[p[k].y] * x[c[k].y];
        float vz = pw[p[k].z] * x[c[k].z];
        float vw = pw[p[k].w] * x[c[k].w];
        atomicAdd(&out[r[k].x], vx);
        atomicAdd(&out[r[k].y], vy);
        atomicAdd(&out[r[k].z], vz);
        atomicAdd(&out[r[k].w], vw);
    }
}

__global__ __launch_bounds__(256) void bias_init_kernel(const float* __restrict__ Pb,
                                                        const int* __restrict__ bp,
                                                        float* __restrict__ out, int n) {
    int i = blockIdx.x * 256 + threadIdx.x;
    if (i < n) out[i] = Pb[bp[i]];
}

// ---------------- Kernel V: val precompute (R9 revert path) ----------------
__global__ __launch_bounds__(256) void val_kernel(
    const float* __restrict__ x, const float* __restrict__ PW, int nparams,
    const int4* __restrict__ cols4, const int4* __restrict__ params4,
    v4f* __restrict__ vals4)
{
    __shared__ float pw[NPARAMS_MAX];
    for (int j = threadIdx.x; j < nparams; j += 256) pw[j] = PW[j];
    __syncthreads();
    const int base = blockIdx.x * (256 * VB) + threadIdx.x;
    int4 c[VB], p[VB];
#pragma unroll
    for (int k = 0; k < VB; ++k) {
        c[k] = cols4[base + k * 256];
        p[k] = params4[base + k * 256];
    }
#pragma unroll
    for (int k = 0; k < VB; ++k) {
        v4f v;
        v.x = pw[p[k].x] * x[c[k].x];
        v.y = pw[p[k].y] * x[c[k].y];
        v.z = pw[p[k].z] * x[c[k].z];
        v.w = pw[p[k].w] * x[c[k].w];
        __builtin_nontemporal_store(v, &vals4[base + k * 256]);
    }
}

// ------- Kernel S: 2-stream scan (R9 revert path) -------
__global__ __launch_bounds__(SCAN_THREADS, 1) void scan4_kernel(
    const int4* __restrict__ rows4, const float4* __restrict__ vals4,
    float* __restrict__ partials, int e4_per_chunk)
{
    __shared__ float acc[SLICE_SIZE];
    const int bid = blockIdx.x;
    const int s = bid / CHUNKS;
    const int c = bid % CHUNKS;
    for (int j = threadIdx.x; j < SLICE_SIZE; j += SCAN_THREADS) acc[j] = 0.0f;
    __syncthreads();

    const int4*   rp = rows4 + (size_t)c * e4_per_chunk;
    const float4* vp = vals4 + (size_t)c * e4_per_chunk;
    const int per_thread = e4_per_chunk / SCAN_THREADS;

    int4   rA[SB4], rB[SB4];
    float4 vA[SB4], vB[SB4];

#define LOAD(dstR, dstV, b0)                                             \
    _Pragma("unroll")                                                    \
    for (int b = 0; b < SB4; ++b) {                                      \
        const int g = ((b0) + b) * SCAN_THREADS + (int)threadIdx.x;      \
        dstR[b] = rp[g];                                                 \
        dstV[b] = vp[g];                                                 \
    }
#define PROC(rX, vX)                                                     \
    _Pragma("unroll")                                                    \
    for (int b = 0; b < SB4; ++b) {                                      \
        if ((rX[b].x >> SLICE_BITS) == s) atomicAdd(&acc[rX[b].x & (SLICE_SIZE - 1)], vX[b].x); \
        if ((rX[b].y >> SLICE_BITS) == s) atomicAdd(&acc[rX[b].y & (SLICE_SIZE - 1)], vX[b].y); \
        if ((rX[b].z >> SLICE_BITS) == s) atomicAdd(&acc[rX[b].z & (SLICE_SIZE - 1)], vX[b].z); \
        if ((rX[b].w >> SLICE_BITS) == s) atomicAdd(&acc[rX[b].w & (SLICE_SIZE - 1)], vX[b].w); \
    }

    LOAD(rA, vA, 0)
    for (int base = 0; base < per_thread; base += 2 * SB4) {
        LOAD(rB, vB, base + SB4)
        PROC(rA, vA)
        if (base + 2 * SB4 < per_thread) {
            LOAD(rA, vA, base + 2 * SB4)
        }
        PROC(rB, vB)
    }
#undef LOAD
#undef PROC
    __syncthreads();

    float* dst = partials + (size_t)bid * SLICE_SIZE;
    for (int j = threadIdx.x; j < SLICE_SIZE; j += SCAN_THREADS) dst[j] = acc[j];
}

// ---------------- Kernel E: reduce partials + bias (R9 revert path) ----------------
__global__ __launch_bounds__(256) void reduce_bias_kernel(
    const float* __restrict__ partials, const float* __restrict__ Pb,
    const int* __restrict__ bp, float* __restrict__ out, int n)
{
    const int i = blockIdx.x * 256 + threadIdx.x;
    if (i >= n) return;
    const int s = i >> SLICE_BITS;
    const int j = i & (SLICE_SIZE - 1);
    const float* p = partials + ((size_t)s * CHUNKS) * SLICE_SIZE + j;
    float sum = 0.0f;
#pragma unroll
    for (int g = 0; g < CHUNKS; ++g) sum += p[(size_t)g * SLICE_SIZE];
    out[i] = sum + Pb[bp[i]];
}

// ---------------- last-resort fallback ----------------
__global__ __launch_bounds__(256) void edge_scatter_kernel(const float* __restrict__ x,
                                                           const float* __restrict__ PW,
                                                           const int* __restrict__ rows,
                                                           const int* __restrict__ cols,
                                                           const int* __restrict__ params,
                                                           float* __restrict__ out, int E) {
    int e = blockIdx.x * 256 + threadIdx.x;
    if (e < E) atomicAdd(out + rows[e], PW[params[e]] * x[cols[e]]);
}

extern "C" void kernel_launch(void* const* d_in, const int* in_sizes, int n_in,
                              void* d_out, int out_size, void* d_ws, size_t ws_size,
                              hipStream_t stream) {
    const float* x        = (const float*)d_in[0];
    const float* Param_W  = (const float*)d_in[1];
    const float* Param_b  = (const float*)d_in[2];
    const int*   w_rows   = (const int*)d_in[3];
    const int*   w_cols   = (const int*)d_in[4];
    const int*   w_params = (const int*)d_in[5];
    const int*   b_params = (const int*)d_in[6];
    float* out = (float*)d_out;

    const int N_  = in_sizes[0];   // 262144
    const int NP_ = in_sizes[1];   // 1280
    const int E_  = in_sizes[3];   // 16777216
    const int e4  = E_ / 4;

    const size_t partial_bytes = (size_t)SLICES * CHUNKS * SLICE_SIZE * sizeof(float); // 32 MiB
    const size_t vals_bytes    = (size_t)E_ * sizeof(float);                            // 64 MiB

    const bool base_ok = (N_ == SLICES * SLICE_SIZE) && (NP_ <= NPARAMS_MAX);

    // single-pass global-atomic path (R14 primary)
    const bool scatter_ok = (NP_ <= NPARAMS_MAX) && (E_ % (4 * 256 * VB) == 0);
    // R9 two-pass path (revert target)
    const bool full_ok = base_ok && (E_ % (4 * 256 * VB) == 0) &&
                         (E_ % (4 * CHUNKS * SCAN_THREADS * 2 * SB4) == 0);

    if (scatter_ok) {
        bias_init_kernel<<<(N_ + 255) / 256, 256, 0, stream>>>(Param_b, b_params, out, N_);
        scatter_atomic_kernel<<<e4 / (256 * VB), 256, 0, stream>>>(
            x, Param_W, NP_, (const int4*)w_rows, (const int4*)w_cols,
            (const int4*)w_params, out);
    } else if (full_ok && ws_size >= vals_bytes + partial_bytes) {
        float*  vals     = (float*)d_ws;
        float*  partials = (float*)((char*)d_ws + vals_bytes);
        const int e4_per_chunk = e4 / CHUNKS;
        val_kernel<<<e4 / (256 * VB), 256, 0, stream>>>(
            x, Param_W, NP_, (const int4*)w_cols, (const int4*)w_params, (v4f*)vals);
        scan4_kernel<<<SLICES * CHUNKS, SCAN_THREADS, 0, stream>>>(
            (const int4*)w_rows, (const float4*)vals, partials, e4_per_chunk);
        reduce_bias_kernel<<<(N_ + 255) / 256, 256, 0, stream>>>(
            partials, Param_b, b_params, out, N_);
    } else {
        bias_init_kernel<<<(N_ + 255) / 256, 256, 0, stream>>>(Param_b, b_params, out, N_);
        edge_scatter_kernel<<<(E_ + 255) / 256, 256, 0, stream>>>(
            x, Param_W, w_rows, w_cols, w_params, out, E_);
    }
}

// Round 7
// 329.212 us; speedup vs baseline: 2.8844x; 2.8844x over previous
//
#include <hip/hip_runtime.h>

// out[i] = sum_{e: rows[e]==i} Param_W[params[e]] * x[cols[e]] + Param_b[b_params[i]]
// N = 262144, E = 16777216, NPARAMS = 1280, NB = 16.
//
// R14 post-mortem: global_atomic_add scatter = 815us; WRITE_SIZE 524MB on a
// 1MB out -> scattered f32 atomics run ~8/cyc device-wide with line-granular
// dirty traffic. Hard negative: memory-side atomics are NOT a path here.
//
// Session model (3 probes): DS-atomic floor ~85us (scan4=107 ~= floor+issue);
// val ~95us (L2-line-bound gather floor ~60); phases do NOT overlap (R10/R13
// both sum-not-max); fixed harness overhead ~125us at any kernel count.
// R15 (resubmit; prior round was an infra failure, container died):
// R9 3-kernel structure (best known, 330) + 3-phase val (all stream loads ->
// all 16 x-gathers in flight -> pw reads -> fmul+nt store).
// Predict val 95->75-90 if ILP-limited (unchanged if L2-line-bound),
// scan4 ~107, total ~310-330.

#define SLICE_BITS  15
#define SLICE_SIZE  (1 << SLICE_BITS)   // 32768
#define SLICES      8
#define CHUNKS      32
#define NPARAMS_MAX 2048
#define SCAN_THREADS 1024
#define SB4         4                   // int4-groups per ping-pong buffer
#define VB          4                   // batched groups per val-kernel thread

typedef float v4f __attribute__((ext_vector_type(4)));

// ---------------- Kernel V: val precompute (3-phase, streaming) ----------------
__global__ __launch_bounds__(256) void val_kernel(
    const float* __restrict__ x, const float* __restrict__ PW, int nparams,
    const int4* __restrict__ cols4, const int4* __restrict__ params4,
    v4f* __restrict__ vals4)
{
    __shared__ float pw[NPARAMS_MAX];
    for (int j = threadIdx.x; j < nparams; j += 256) pw[j] = PW[j];
    __syncthreads();
    const int base = blockIdx.x * (256 * VB) + threadIdx.x;

    // phase 1: stream index loads (coalesced 16B)
    int4 c[VB], p[VB];
#pragma unroll
    for (int k = 0; k < VB; ++k) {
        c[k] = cols4[base + k * 256];
        p[k] = params4[base + k * 256];
    }
    // phase 2: issue ALL x gathers back-to-back (16 loads in flight/thread)
    float gx[VB][4];
#pragma unroll
    for (int k = 0; k < VB; ++k) {
        gx[k][0] = x[c[k].x];
        gx[k][1] = x[c[k].y];
        gx[k][2] = x[c[k].z];
        gx[k][3] = x[c[k].w];
    }
    // phase 3: pw LDS reads (random over 1280 words ~ 2 lanes/bank: free)
    float gw[VB][4];
#pragma unroll
    for (int k = 0; k < VB; ++k) {
        gw[k][0] = pw[p[k].x];
        gw[k][1] = pw[p[k].y];
        gw[k][2] = pw[p[k].z];
        gw[k][3] = pw[p[k].w];
    }
    // phase 4: fmul + nontemporal store (don't evict x's L2 footprint)
#pragma unroll
    for (int k = 0; k < VB; ++k) {
        v4f v;
        v.x = gw[k][0] * gx[k][0];
        v.y = gw[k][1] * gx[k][1];
        v.z = gw[k][2] * gx[k][2];
        v.w = gw[k][3] * gx[k][3];
        __builtin_nontemporal_store(v, &vals4[base + k * 256]);
    }
}

// ------- Kernel S: 2-stream scan, ping-pong prefetch + predicated adds -------
__global__ __launch_bounds__(SCAN_THREADS, 1) void scan4_kernel(
    const int4* __restrict__ rows4, const float4* __restrict__ vals4,
    float* __restrict__ partials, int e4_per_chunk)
{
    __shared__ float acc[SLICE_SIZE];    // 128 KiB -> 1 block/CU
    const int bid = blockIdx.x;
    const int s = bid / CHUNKS;          // slice
    const int c = bid % CHUNKS;          // chunk; bid%8 == c%8 -> the 8 readers of a
                                         // chunk co-locate on one XCD (round-robin)
    for (int j = threadIdx.x; j < SLICE_SIZE; j += SCAN_THREADS) acc[j] = 0.0f;
    __syncthreads();

    const int4*   rp = rows4 + (size_t)c * e4_per_chunk;
    const float4* vp = vals4 + (size_t)c * e4_per_chunk;
    const int per_thread = e4_per_chunk / SCAN_THREADS;   // 128

    int4   rA[SB4], rB[SB4];
    float4 vA[SB4], vB[SB4];

#define LOAD(dstR, dstV, b0)                                             \
    _Pragma("unroll")                                                    \
    for (int b = 0; b < SB4; ++b) {                                      \
        const int g = ((b0) + b) * SCAN_THREADS + (int)threadIdx.x;      \
        dstR[b] = rp[g];                                                 \
        dstV[b] = vp[g];                                                 \
    }
#define PROC(rX, vX)                                                     \
    _Pragma("unroll")                                                    \
    for (int b = 0; b < SB4; ++b) {                                      \
        if ((rX[b].x >> SLICE_BITS) == s) atomicAdd(&acc[rX[b].x & (SLICE_SIZE - 1)], vX[b].x); \
        if ((rX[b].y >> SLICE_BITS) == s) atomicAdd(&acc[rX[b].y & (SLICE_SIZE - 1)], vX[b].y); \
        if ((rX[b].z >> SLICE_BITS) == s) atomicAdd(&acc[rX[b].z & (SLICE_SIZE - 1)], vX[b].z); \
        if ((rX[b].w >> SLICE_BITS) == s) atomicAdd(&acc[rX[b].w & (SLICE_SIZE - 1)], vX[b].w); \
    }

    LOAD(rA, vA, 0)
    for (int base = 0; base < per_thread; base += 2 * SB4) {
        LOAD(rB, vB, base + SB4)           // in flight while A's atomics issue
        PROC(rA, vA)
        if (base + 2 * SB4 < per_thread) {
            LOAD(rA, vA, base + 2 * SB4)   // in flight while B's atomics issue
        }
        PROC(rB, vB)
    }
#undef LOAD
#undef PROC
    __syncthreads();

    float* dst = partials + (size_t)bid * SLICE_SIZE;
    for (int j = threadIdx.x; j < SLICE_SIZE; j += SCAN_THREADS) dst[j] = acc[j];
}

// ---------------- Kernel E: reduce partials + bias ----------------
__global__ __launch_bounds__(256) void reduce_bias_kernel(
    const float* __restrict__ partials, const float* __restrict__ Pb,
    const int* __restrict__ bp, float* __restrict__ out, int n)
{
    const int i = blockIdx.x * 256 + threadIdx.x;
    if (i >= n) return;
    const int s = i >> SLICE_BITS;
    const int j = i & (SLICE_SIZE - 1);
    const float* p = partials + ((size_t)s * CHUNKS) * SLICE_SIZE + j;
    float sum = 0.0f;
#pragma unroll
    for (int g = 0; g < CHUNKS; ++g) sum += p[(size_t)g * SLICE_SIZE];
    out[i] = sum + Pb[bp[i]];
}

// ---------------- last-resort fallbacks ----------------
__global__ __launch_bounds__(256) void bias_init_kernel(const float* __restrict__ Pb,
                                                        const int* __restrict__ bp,
                                                        float* __restrict__ out, int n) {
    int i = blockIdx.x * 256 + threadIdx.x;
    if (i < n) out[i] = Pb[bp[i]];
}

__global__ __launch_bounds__(256) void edge_scatter_kernel(const float* __restrict__ x,
                                                           const float* __restrict__ PW,
                                                           const int* __restrict__ rows,
                                                           const int* __restrict__ cols,
                                                           const int* __restrict__ params,
                                                           float* __restrict__ out, int E) {
    int e = blockIdx.x * 256 + threadIdx.x;
    if (e < E) atomicAdd(out + rows[e], PW[params[e]] * x[cols[e]]);
}

extern "C" void kernel_launch(void* const* d_in, const int* in_sizes, int n_in,
                              void* d_out, int out_size, void* d_ws, size_t ws_size,
                              hipStream_t stream) {
    const float* x        = (const float*)d_in[0];
    const float* Param_W  = (const float*)d_in[1];
    const float* Param_b  = (const float*)d_in[2];
    const int*   w_rows   = (const int*)d_in[3];
    const int*   w_cols   = (const int*)d_in[4];
    const int*   w_params = (const int*)d_in[5];
    const int*   b_params = (const int*)d_in[6];
    float* out = (float*)d_out;

    const int N_  = in_sizes[0];   // 262144
    const int NP_ = in_sizes[1];   // 1280
    const int E_  = in_sizes[3];   // 16777216
    const int e4  = E_ / 4;

    const size_t partial_bytes = (size_t)SLICES * CHUNKS * SLICE_SIZE * sizeof(float); // 32 MiB
    const size_t vals_bytes    = (size_t)E_ * sizeof(float);                            // 64 MiB
    const bool shapes_ok = (N_ == SLICES * SLICE_SIZE) && (NP_ <= NPARAMS_MAX) &&
                           (E_ % (4 * 256 * VB) == 0) &&
                           (E_ % (4 * CHUNKS * SCAN_THREADS * 2 * SB4) == 0);

    if (shapes_ok && ws_size >= vals_bytes + partial_bytes) {
        float*  vals     = (float*)d_ws;
        float*  partials = (float*)((char*)d_ws + vals_bytes);
        const int e4_per_chunk = e4 / CHUNKS;   // 131072
        val_kernel<<<e4 / (256 * VB), 256, 0, stream>>>(
            x, Param_W, NP_, (const int4*)w_cols, (const int4*)w_params, (v4f*)vals);
        scan4_kernel<<<SLICES * CHUNKS, SCAN_THREADS, 0, stream>>>(
            (const int4*)w_rows, (const float4*)vals, partials, e4_per_chunk);
        reduce_bias_kernel<<<(N_ + 255) / 256, 256, 0, stream>>>(
            partials, Param_b, b_params, out, N_);
    } else {
        bias_init_kernel<<<(N_ + 255) / 256, 256, 0, stream>>>(Param_b, b_params, out, N_);
        edge_scatter_kernel<<<(E_ + 255) / 256, 256, 0, stream>>>(
            x, Param_W, w_rows, w_cols, w_params, out, E_);
    }
}